// Round 2
// 2712.491 us; speedup vs baseline: 1.1444x; 1.1444x over previous
//
#include <hip/hip_runtime.h>
#include <hip/hip_fp16.h>
#include <math.h>

#define B_ 64
#define T_ 512

typedef _Float16 h2_t __attribute__((ext_vector_type(2)));

__device__ __forceinline__ float fdot2u(unsigned int a, unsigned int b, float c) {
#if __has_builtin(__builtin_amdgcn_fdot2)
    return __builtin_amdgcn_fdot2(__builtin_bit_cast(h2_t, a),
                                  __builtin_bit_cast(h2_t, b), c, false);
#else
    const __half2 ah = __builtin_bit_cast(__half2, a);
    const __half2 bh = __builtin_bit_cast(__half2, b);
    const float2 af = __half22float2(ah), bf = __half22float2(bh);
    return c + af.x * bf.x + af.y * bf.y;
#endif
}
__device__ __forceinline__ unsigned int pack_h2(float x, float y) {
    const __half2 h = __float22half2_rn(make_float2(x, y));
    return __builtin_bit_cast(unsigned int, h);
}
__device__ __forceinline__ float ubits(unsigned int a) { return __builtin_bit_cast(float, a); }
__device__ __forceinline__ unsigned short f2h_bits(float x) {
    return __builtin_bit_cast(unsigned short, (_Float16)x);
}
__device__ __forceinline__ float h2f_bits(unsigned int bits) {
    return (float)__builtin_bit_cast(_Float16, (unsigned short)(bits & 0xffffu));
}

__device__ __forceinline__ float fsig(float z) { return 1.f / (1.f + __expf(-z)); }
__device__ __forceinline__ float ftanh(float z) {
    const float e = __expf(2.f * z);
    return 1.f - 2.f / (e + 1.f);
}

// ---------------------------------------------------------------------------
// GEMM v2: C[M,N] = (A[M,K]*mask)@W[K,N] + bias, packed-fp16 dot2 inner loop.
// 64x64 tile, TK=32 (16 k-pairs), 256 threads, 4x4 microtile. (unchanged)
// ---------------------------------------------------------------------------
__global__ __launch_bounds__(256) void gemm_mask_f16(
    const float* __restrict__ A, const float* __restrict__ W,
    const float* __restrict__ bias, const float* __restrict__ mask,
    float* __restrict__ C, int M, int N, int K)
{
    const int TM = 64, TN = 64, TK = 32, KP = 16;
    __shared__ __align__(16) unsigned int As2[KP][68];
    __shared__ __align__(16) unsigned int Bs2[KP][68];

    const int tid = threadIdx.x;
    const int bn = blockIdx.x;
    const int bm = blockIdx.y;
    const int row0 = bm * TM;
    const int b = row0 / T_;

    const int ty = tid >> 4;
    const int tx = tid & 15;
    const int m0 = ty * 4;
    const int n0 = tx * 4;

    float acc[4][4];
#pragma unroll
    for (int i = 0; i < 4; i++)
#pragma unroll
        for (int j = 0; j < 4; j++) acc[i][j] = 0.f;

    for (int kk = 0; kk < K; kk += TK) {
        {
            const int m = tid >> 2;
            const int kq = (tid & 3) * 8;
            const float4 mv0 = *(const float4*)(mask + (size_t)b * K + kk + kq);
            const float4 mv1 = *(const float4*)(mask + (size_t)b * K + kk + kq + 4);
            const float4 a0 = *(const float4*)(A + (size_t)(row0 + m) * K + kk + kq);
            const float4 a1 = *(const float4*)(A + (size_t)(row0 + m) * K + kk + kq + 4);
            As2[kq / 2 + 0][m] = pack_h2(a0.x * mv0.x, a0.y * mv0.y);
            As2[kq / 2 + 1][m] = pack_h2(a0.z * mv0.z, a0.w * mv0.w);
            As2[kq / 2 + 2][m] = pack_h2(a1.x * mv1.x, a1.y * mv1.y);
            As2[kq / 2 + 3][m] = pack_h2(a1.z * mv1.z, a1.w * mv1.w);
        }
        {
            const int kp = tid >> 4;
            const int nq = (tid & 15) * 4;
            const float4 w0 = *(const float4*)(W + (size_t)(kk + 2 * kp) * N + bn * TN + nq);
            const float4 w1 = *(const float4*)(W + (size_t)(kk + 2 * kp + 1) * N + bn * TN + nq);
            uint4 pv;
            pv.x = pack_h2(w0.x, w1.x);
            pv.y = pack_h2(w0.y, w1.y);
            pv.z = pack_h2(w0.z, w1.z);
            pv.w = pack_h2(w0.w, w1.w);
            *(uint4*)&Bs2[kp][nq] = pv;
        }
        __syncthreads();

#pragma unroll
        for (int kp = 0; kp < KP; kp++) {
            const uint4 a4 = *(const uint4*)&As2[kp][m0];
            const uint4 b4 = *(const uint4*)&Bs2[kp][n0];
            acc[0][0] = fdot2u(a4.x, b4.x, acc[0][0]); acc[0][1] = fdot2u(a4.x, b4.y, acc[0][1]);
            acc[0][2] = fdot2u(a4.x, b4.z, acc[0][2]); acc[0][3] = fdot2u(a4.x, b4.w, acc[0][3]);
            acc[1][0] = fdot2u(a4.y, b4.x, acc[1][0]); acc[1][1] = fdot2u(a4.y, b4.y, acc[1][1]);
            acc[1][2] = fdot2u(a4.y, b4.z, acc[1][2]); acc[1][3] = fdot2u(a4.y, b4.w, acc[1][3]);
            acc[2][0] = fdot2u(a4.z, b4.x, acc[2][0]); acc[2][1] = fdot2u(a4.z, b4.y, acc[2][1]);
            acc[2][2] = fdot2u(a4.z, b4.z, acc[2][2]); acc[2][3] = fdot2u(a4.z, b4.w, acc[2][3]);
            acc[3][0] = fdot2u(a4.w, b4.x, acc[3][0]); acc[3][1] = fdot2u(a4.w, b4.y, acc[3][1]);
            acc[3][2] = fdot2u(a4.w, b4.z, acc[3][2]); acc[3][3] = fdot2u(a4.w, b4.w, acc[3][3]);
        }
        __syncthreads();
    }

    const float4 bv = *(const float4*)(bias + bn * TN + n0);
#pragma unroll
    for (int i = 0; i < 4; i++) {
        float4 v;
        v.x = acc[i][0] + bv.x;
        v.y = acc[i][1] + bv.y;
        v.z = acc[i][2] + bv.z;
        v.w = acc[i][3] + bv.w;
        *(float4*)&C[(size_t)(row0 + m0 + i) * N + bn * TN + n0] = v;
    }
}

// ---------------------------------------------------------------------------
// LSTM recurrence v11 = v10 with U moved from LDS into per-thread REGISTERS.
// v10's dot phase was LDS-issue-bound: 256x ds_read_b64 (U) + 64x ds_read_b128
// (hW) per CU per step ~= 2000 cycles of LDS-unit occupancy (SQ_LDS_BANK_
// CONFLICT=0 -> pure issue bandwidth, not conflicts). U is loop-invariant over
// all 512 steps, so each thread now loads its 2-column k-slice ONCE into
// uint2 ur[WPT] (32 VGPR for HN=256/f16, 16 for HN=128/f32) via coalesced
// float2 global reads, and the per-step dot is 32 fdot2 + 4 wave-uniform
// b128 hW broadcasts only. UW2 (128 KB) is gone -> LDS ~9 KB. VGPR 52->~90
// (must stay <=128 for the 1024-thread block). Exchange protocol (tagged
// words, parity double-buffer, 3 barriers) identical to v10.
// ---------------------------------------------------------------------------
template <int HN, bool F16>
__global__ __launch_bounds__(1024) void lstm_rec_v11(
    const float* __restrict__ xz,       // [B, T, 4*HN]
    const float* __restrict__ U,        // [HN, 4*HN]
    float* __restrict__ hout,           // [B, T, HN] or nullptr
    float* __restrict__ out_last,       // [B, HN] or nullptr
    unsigned int* __restrict__ hbuf)    // [2][B_*HN] tagged words
{
    constexpr int GATES = 4 * HN;
    constexpr int COLS = HN;
    constexpr int CP = COLS / 2;
    constexpr int NKG = 1024 / CP;
    constexpr int KH = HN / NKG;
    constexpr int HB = HN / 4;
    constexpr int KWORDS = F16 ? HN / 2 : HN;
    constexpr int WPT = F16 ? KH / 2 : KH;

    __shared__ __align__(16) unsigned int hW[KWORDS];
    __shared__ __align__(16) float2 zpart[(NKG - 1) * CP];
    __shared__ __align__(16) float act_sh[COLS];

    const int tid = threadIdx.x;
    const int q = blockIdx.x >> 6;      // quarter 0..3
    const int b = blockIdx.x & 63;      // batch element (siblings share an XCD)

    const int cp = tid % CP;
    const int kq = tid / CP;            // wave-uniform (CP % 64 == 0)
    const int c0 = 2 * cp;
    const int group = c0 / HB;
    const int gcol = group * HN + q * HB + (c0 % HB);
    const int wbase = kq * WPT;
    const bool red_grp = (kq == NKG - 1);

    // ---- one-time: load this thread's U slice into REGISTERS ----
    // ur[j].x packs k-word (wbase+j) for column gcol, .y for column gcol+1.
    // (c0 is even, so gcol/gcol+1 are in the same gate group and float2-aligned.)
    uint2 ur[WPT];
#pragma unroll
    for (int j = 0; j < WPT; ++j) {
        const int w = wbase + j;
        if constexpr (F16) {
            const float2 r0 = *(const float2*)(U + (size_t)(2 * w) * GATES + gcol);
            const float2 r1 = *(const float2*)(U + (size_t)(2 * w + 1) * GATES + gcol);
            ur[j].x = pack_h2(r0.x, r1.x);
            ur[j].y = pack_h2(r0.y, r1.y);
        } else {
            const float2 r0 = *(const float2*)(U + (size_t)w * GATES + gcol);
            ur[j].x = __builtin_bit_cast(unsigned int, r0.x);
            ur[j].y = __builtin_bit_cast(unsigned int, r0.y);
        }
    }

    if (tid < KWORDS) hW[tid] = 0u;     // h_0 = 0
    float cst = 0.f;

    const float* xzb = xz + (size_t)b * T_ * GATES + gcol;
    const bool tanh_gate = (group == 2);

    float2 z0 = make_float2(0.f, 0.f);
    if (red_grp) z0 = *(const float2*)xzb;   // step-0 xz
    __syncthreads();

#pragma unroll 1
    for (int t = 0; t < T_; ++t) {
        // ---- dot: z[c0,c0+1] over this thread's k-words (U in regs, h from LDS) ----
        float acc0 = 0.f, acc1 = 0.f;
#pragma unroll
        for (int j = 0; j < WPT; j += 4) {
            const int w = wbase + j;
            const uint4 hw4 = *(const uint4*)&hW[w];    // wave-uniform broadcast
            if constexpr (F16) {
                acc0 = fdot2u(ur[j + 0].x, hw4.x, acc0); acc1 = fdot2u(ur[j + 0].y, hw4.x, acc1);
                acc0 = fdot2u(ur[j + 1].x, hw4.y, acc0); acc1 = fdot2u(ur[j + 1].y, hw4.y, acc1);
                acc0 = fdot2u(ur[j + 2].x, hw4.z, acc0); acc1 = fdot2u(ur[j + 2].y, hw4.z, acc1);
                acc0 = fdot2u(ur[j + 3].x, hw4.w, acc0); acc1 = fdot2u(ur[j + 3].y, hw4.w, acc1);
            } else {
                acc0 += ubits(ur[j + 0].x) * ubits(hw4.x); acc1 += ubits(ur[j + 0].y) * ubits(hw4.x);
                acc0 += ubits(ur[j + 1].x) * ubits(hw4.y); acc1 += ubits(ur[j + 1].y) * ubits(hw4.y);
                acc0 += ubits(ur[j + 2].x) * ubits(hw4.z); acc1 += ubits(ur[j + 2].y) * ubits(hw4.z);
                acc0 += ubits(ur[j + 3].x) * ubits(hw4.w); acc1 += ubits(ur[j + 3].y) * ubits(hw4.w);
            }
        }
        if (!red_grp) zpart[kq * CP + cp] = make_float2(acc0, acc1);
        __syncthreads();    // bar1

        // ---- reduce + activations + xz prefetch (last k-group) ----
        if (red_grp) {
            float zx = z0.x + acc0;
            float zy = z0.y + acc1;
#pragma unroll
            for (int r = 0; r < NKG - 1; ++r) {
                const float2 p = zpart[r * CP + cp];
                zx += p.x; zy += p.y;
            }
            if (t + 1 < T_) z0 = *(const float2*)(xzb + (size_t)(t + 1) * GATES);
            float ax, ay;
            if (tanh_gate) { ax = ftanh(zx); ay = ftanh(zy); }
            else           { ax = fsig(zx);  ay = fsig(zy);  }
            *(float2*)&act_sh[c0] = make_float2(ax, ay);
        }
        __syncthreads();    // bar2

        // ---- cell update (wave 0, lanes < HB) ----
        float hnew = 0.f;
        if (tid < HB) {
            const float ig = act_sh[tid];
            const float fg = act_sh[HB + tid];
            const float gg = act_sh[2 * HB + tid];
            const float og = act_sh[3 * HB + tid];
            cst = fg * cst + ig * gg;
            hnew = og * ftanh(cst);
            if (out_last && t == T_ - 1) out_last[(size_t)b * HN + q * HB + tid] = hnew;
        }

        if (t < T_ - 1) {
            const int s = t & 1;
            unsigned int* hslot = hbuf + (size_t)s * B_ * HN + b * HN;
            const unsigned int tag = (unsigned int)(t + 1);

            // publish own h slice as tagged words (no fence, no vmcnt, no flag)
            if (tid < HB) {
                const unsigned int word = (tag << 16) | (unsigned int)f2h_bits(hnew);
                __hip_atomic_store(&hslot[q * HB + tid], word,
                                   __ATOMIC_RELAXED, __HIP_MEMORY_SCOPE_AGENT);
            }
            // hout store (off critical path, cached)
            if (hout && tid < HB)
                hout[((size_t)b * T_ + t) * HN + q * HB + tid] = hnew;

            // pull full h: load + retry until tags fresh (wave 0)
            if (tid < 64) {
                const unsigned long long* hq = (const unsigned long long*)hslot;
                if constexpr (F16) {
                    // lane: words 4*tid .. 4*tid+3 (two qwords)
                    unsigned long long vA = __hip_atomic_load(&hq[2 * tid],
                        __ATOMIC_RELAXED, __HIP_MEMORY_SCOPE_AGENT);
                    unsigned long long vB = __hip_atomic_load(&hq[2 * tid + 1],
                        __ATOMIC_RELAXED, __HIP_MEMORY_SCOPE_AGENT);
                    while (((vA >> 16) & 0xffffu) != tag || (vA >> 48) != tag)
                        vA = __hip_atomic_load(&hq[2 * tid],
                            __ATOMIC_RELAXED, __HIP_MEMORY_SCOPE_AGENT);
                    while (((vB >> 16) & 0xffffu) != tag || (vB >> 48) != tag)
                        vB = __hip_atomic_load(&hq[2 * tid + 1],
                            __ATOMIC_RELAXED, __HIP_MEMORY_SCOPE_AGENT);
                    hW[2 * tid] = (unsigned int)(vA & 0xffffu) |
                                  ((unsigned int)((vA >> 32) & 0xffffu) << 16);
                    hW[2 * tid + 1] = (unsigned int)(vB & 0xffffu) |
                                      ((unsigned int)((vB >> 32) & 0xffffu) << 16);
                } else {
                    // HN=128: lane: words 2*tid, 2*tid+1 (one qword)
                    unsigned long long v = __hip_atomic_load(&hq[tid],
                        __ATOMIC_RELAXED, __HIP_MEMORY_SCOPE_AGENT);
                    while (((v >> 16) & 0xffffu) != tag || (v >> 48) != tag)
                        v = __hip_atomic_load(&hq[tid],
                            __ATOMIC_RELAXED, __HIP_MEMORY_SCOPE_AGENT);
                    hW[2 * tid] = __builtin_bit_cast(unsigned int,
                        h2f_bits((unsigned int)v));
                    hW[2 * tid + 1] = __builtin_bit_cast(unsigned int,
                        h2f_bits((unsigned int)(v >> 32)));
                }
            }
            __syncthreads();    // bar3
        } else if (hout && tid < HB) {
            hout[((size_t)b * T_ + t) * HN + q * HB + tid] = hnew;
        }
    }
}

// ---------------------------------------------------------------------------
// Launch
// ---------------------------------------------------------------------------
extern "C" void kernel_launch(void* const* d_in, const int* in_sizes, int n_in,
                              void* d_out, int out_size, void* d_ws, size_t ws_size,
                              hipStream_t stream)
{
    const float* x  = (const float*)d_in[0];
    const float* W0 = (const float*)d_in[1];
    const float* U0 = (const float*)d_in[2];
    const float* b0 = (const float*)d_in[3];
    const float* W1 = (const float*)d_in[4];
    const float* U1 = (const float*)d_in[5];
    const float* b1 = (const float*)d_in[6];
    const float* W2 = (const float*)d_in[7];
    const float* U2 = (const float*)d_in[8];
    const float* b2 = (const float*)d_in[9];
    const float* m0 = (const float*)d_in[10];
    const float* m1 = (const float*)d_in[11];
    const float* m2 = (const float*)d_in[12];
    float* out = (float*)d_out;

    // workspace layout:
    //   xz    : 134217728 B   (64*512*1024 floats, reused by all 3 layers)
    //   h0    :  33554432 B
    //   h1    :  33554432 B
    //   hbuf  : 3 regions x 131072 B (2 x 64 x 256 tagged words per layer)
    char* ws = (char*)d_ws;
    float* xz = (float*)ws;
    float* h0 = (float*)(ws + 134217728);
    float* h1 = (float*)(ws + 134217728 + 33554432);
    unsigned int* hb0 = (unsigned int*)(ws + 134217728 + 2 * 33554432);
    unsigned int* hb1 = hb0 + 2 * B_ * 256;
    unsigned int* hb2 = hb1 + 2 * B_ * 256;

    const int M = B_ * T_;  // 32768

    // Layer 0
    gemm_mask_f16<<<dim3(1024 / 64, M / 64), 256, 0, stream>>>(x, W0, b0, m0, xz, M, 1024, 128);
    lstm_rec_v11<256, true><<<256, 1024, 0, stream>>>(xz, U0, h0, nullptr, hb0);

    // Layer 1
    gemm_mask_f16<<<dim3(1024 / 64, M / 64), 256, 0, stream>>>(h0, W1, b1, m1, xz, M, 1024, 256);
    lstm_rec_v11<256, true><<<256, 1024, 0, stream>>>(xz, U1, h1, nullptr, hb1);

    // Layer 2 (H=128, fp32 compute, fp16 exchange), emit last h only
    gemm_mask_f16<<<dim3(512 / 64, M / 64), 256, 0, stream>>>(h1, W2, b2, m2, xz, M, 512, 256);
    lstm_rec_v11<128, false><<<256, 1024, 0, stream>>>(xz, U2, nullptr, out, hb2);
}

// Round 3
// 2668.336 us; speedup vs baseline: 1.1633x; 1.0165x over previous
//
#include <hip/hip_runtime.h>
#include <hip/hip_fp16.h>
#include <math.h>

#define B_ 64
#define T_ 512

typedef _Float16 h2_t __attribute__((ext_vector_type(2)));

__device__ __forceinline__ float fdot2u(unsigned int a, unsigned int b, float c) {
#if __has_builtin(__builtin_amdgcn_fdot2)
    return __builtin_amdgcn_fdot2(__builtin_bit_cast(h2_t, a),
                                  __builtin_bit_cast(h2_t, b), c, false);
#else
    const __half2 ah = __builtin_bit_cast(__half2, a);
    const __half2 bh = __builtin_bit_cast(__half2, b);
    const float2 af = __half22float2(ah), bf = __half22float2(bh);
    return c + af.x * bf.x + af.y * bf.y;
#endif
}
__device__ __forceinline__ unsigned int pack_h2(float x, float y) {
    const __half2 h = __float22half2_rn(make_float2(x, y));
    return __builtin_bit_cast(unsigned int, h);
}
__device__ __forceinline__ float ubits(unsigned int a) { return __builtin_bit_cast(float, a); }
__device__ __forceinline__ unsigned short f2h_bits(float x) {
    return __builtin_bit_cast(unsigned short, (_Float16)x);
}
__device__ __forceinline__ float h2f_bits(unsigned int bits) {
    return (float)__builtin_bit_cast(_Float16, (unsigned short)(bits & 0xffffu));
}

__device__ __forceinline__ float fsig(float z) { return 1.f / (1.f + __expf(-z)); }
__device__ __forceinline__ float ftanh(float z) {
    const float e = __expf(2.f * z);
    return 1.f - 2.f / (e + 1.f);
}

// LDS-only barrier: __syncthreads() makes hipcc emit `s_waitcnt vmcnt(0)
// lgkmcnt(0)` before s_barrier, draining ALL outstanding global ops (hout
// stores, publish atomics, xz prefetch) into the critical path 3x per step.
// The three in-loop barriers only protect LDS (zpart/act_sh/hW), so
// lgkmcnt(0) alone is the correct fence. Memory clobbers on both sides pin
// compile-time ordering (rule #18: loads must not hoist past the barrier).
__device__ __forceinline__ void bar_lds() {
    asm volatile("s_waitcnt lgkmcnt(0)" ::: "memory");
    __builtin_amdgcn_s_barrier();
    asm volatile("" ::: "memory");
}

// ---------------------------------------------------------------------------
// GEMM v2: C[M,N] = (A[M,K]*mask)@W[K,N] + bias, packed-fp16 dot2 inner loop.
// 64x64 tile, TK=32 (16 k-pairs), 256 threads, 4x4 microtile. (unchanged)
// ---------------------------------------------------------------------------
__global__ __launch_bounds__(256) void gemm_mask_f16(
    const float* __restrict__ A, const float* __restrict__ W,
    const float* __restrict__ bias, const float* __restrict__ mask,
    float* __restrict__ C, int M, int N, int K)
{
    const int TM = 64, TN = 64, TK = 32, KP = 16;
    __shared__ __align__(16) unsigned int As2[KP][68];
    __shared__ __align__(16) unsigned int Bs2[KP][68];

    const int tid = threadIdx.x;
    const int bn = blockIdx.x;
    const int bm = blockIdx.y;
    const int row0 = bm * TM;
    const int b = row0 / T_;

    const int ty = tid >> 4;
    const int tx = tid & 15;
    const int m0 = ty * 4;
    const int n0 = tx * 4;

    float acc[4][4];
#pragma unroll
    for (int i = 0; i < 4; i++)
#pragma unroll
        for (int j = 0; j < 4; j++) acc[i][j] = 0.f;

    for (int kk = 0; kk < K; kk += TK) {
        {
            const int m = tid >> 2;
            const int kq = (tid & 3) * 8;
            const float4 mv0 = *(const float4*)(mask + (size_t)b * K + kk + kq);
            const float4 mv1 = *(const float4*)(mask + (size_t)b * K + kk + kq + 4);
            const float4 a0 = *(const float4*)(A + (size_t)(row0 + m) * K + kk + kq);
            const float4 a1 = *(const float4*)(A + (size_t)(row0 + m) * K + kk + kq + 4);
            As2[kq / 2 + 0][m] = pack_h2(a0.x * mv0.x, a0.y * mv0.y);
            As2[kq / 2 + 1][m] = pack_h2(a0.z * mv0.z, a0.w * mv0.w);
            As2[kq / 2 + 2][m] = pack_h2(a1.x * mv1.x, a1.y * mv1.y);
            As2[kq / 2 + 3][m] = pack_h2(a1.z * mv1.z, a1.w * mv1.w);
        }
        {
            const int kp = tid >> 4;
            const int nq = (tid & 15) * 4;
            const float4 w0 = *(const float4*)(W + (size_t)(kk + 2 * kp) * N + bn * TN + nq);
            const float4 w1 = *(const float4*)(W + (size_t)(kk + 2 * kp + 1) * N + bn * TN + nq);
            uint4 pv;
            pv.x = pack_h2(w0.x, w1.x);
            pv.y = pack_h2(w0.y, w1.y);
            pv.z = pack_h2(w0.z, w1.z);
            pv.w = pack_h2(w0.w, w1.w);
            *(uint4*)&Bs2[kp][nq] = pv;
        }
        __syncthreads();

#pragma unroll
        for (int kp = 0; kp < KP; kp++) {
            const uint4 a4 = *(const uint4*)&As2[kp][m0];
            const uint4 b4 = *(const uint4*)&Bs2[kp][n0];
            acc[0][0] = fdot2u(a4.x, b4.x, acc[0][0]); acc[0][1] = fdot2u(a4.x, b4.y, acc[0][1]);
            acc[0][2] = fdot2u(a4.x, b4.z, acc[0][2]); acc[0][3] = fdot2u(a4.x, b4.w, acc[0][3]);
            acc[1][0] = fdot2u(a4.y, b4.x, acc[1][0]); acc[1][1] = fdot2u(a4.y, b4.y, acc[1][1]);
            acc[1][2] = fdot2u(a4.y, b4.z, acc[1][2]); acc[1][3] = fdot2u(a4.y, b4.w, acc[1][3]);
            acc[2][0] = fdot2u(a4.z, b4.x, acc[2][0]); acc[2][1] = fdot2u(a4.z, b4.y, acc[2][1]);
            acc[2][2] = fdot2u(a4.z, b4.z, acc[2][2]); acc[2][3] = fdot2u(a4.z, b4.w, acc[2][3]);
            acc[3][0] = fdot2u(a4.w, b4.x, acc[3][0]); acc[3][1] = fdot2u(a4.w, b4.y, acc[3][1]);
            acc[3][2] = fdot2u(a4.w, b4.z, acc[3][2]); acc[3][3] = fdot2u(a4.w, b4.w, acc[3][3]);
        }
        __syncthreads();
    }

    const float4 bv = *(const float4*)(bias + bn * TN + n0);
#pragma unroll
    for (int i = 0; i < 4; i++) {
        float4 v;
        v.x = acc[i][0] + bv.x;
        v.y = acc[i][1] + bv.y;
        v.z = acc[i][2] + bv.z;
        v.w = acc[i][3] + bv.w;
        *(float4*)&C[(size_t)(row0 + m0 + i) * N + bn * TN + n0] = v;
    }
}

// ---------------------------------------------------------------------------
// LSTM recurrence v12 = v11 with the three in-loop __syncthreads() replaced
// by bar_lds() (lgkmcnt(0)-only barrier). v11's step was ~3783 cyc with all
// pipes near-idle (VALUBusy 20%, HBM 2%): the missing time is the compiler's
// implicit `s_waitcnt vmcnt(0)` drain before each s_barrier, which pulls the
// hout store, publish atomic, and xz prefetch latencies INTO the critical
// path 3x/step. The in-loop barriers only guard LDS (zpart/act_sh/hW);
// lgkmcnt(0) is the sufficient fence. Exchange protocol correctness is
// unchanged: the tag travels atomically with the data, same-thread
// same-address stores are ordered, and the parity skew bound is a data-
// dependency argument (partner cannot publish t+3 into a slot before it
// consumed my t+1), fence-free. Pull/z0 loads get auto waitcnt at first use.
// ---------------------------------------------------------------------------
template <int HN, bool F16>
__global__ __launch_bounds__(1024) void lstm_rec_v12(
    const float* __restrict__ xz,       // [B, T, 4*HN]
    const float* __restrict__ U,        // [HN, 4*HN]
    float* __restrict__ hout,           // [B, T, HN] or nullptr
    float* __restrict__ out_last,       // [B, HN] or nullptr
    unsigned int* __restrict__ hbuf)    // [2][B_*HN] tagged words
{
    constexpr int GATES = 4 * HN;
    constexpr int COLS = HN;
    constexpr int CP = COLS / 2;
    constexpr int NKG = 1024 / CP;
    constexpr int KH = HN / NKG;
    constexpr int HB = HN / 4;
    constexpr int KWORDS = F16 ? HN / 2 : HN;
    constexpr int WPT = F16 ? KH / 2 : KH;

    __shared__ __align__(16) unsigned int hW[KWORDS];
    __shared__ __align__(16) float2 zpart[(NKG - 1) * CP];
    __shared__ __align__(16) float act_sh[COLS];

    const int tid = threadIdx.x;
    const int q = blockIdx.x >> 6;      // quarter 0..3
    const int b = blockIdx.x & 63;      // batch element (siblings 64 apart -> same XCD)

    const int cp = tid % CP;
    const int kq = tid / CP;            // wave-uniform (CP % 64 == 0)
    const int c0 = 2 * cp;
    const int group = c0 / HB;
    const int gcol = group * HN + q * HB + (c0 % HB);
    const int wbase = kq * WPT;
    const bool red_grp = (kq == NKG - 1);

    // ---- one-time: load this thread's U slice into REGISTERS ----
    uint2 ur[WPT];
#pragma unroll
    for (int j = 0; j < WPT; ++j) {
        const int w = wbase + j;
        if constexpr (F16) {
            const float2 r0 = *(const float2*)(U + (size_t)(2 * w) * GATES + gcol);
            const float2 r1 = *(const float2*)(U + (size_t)(2 * w + 1) * GATES + gcol);
            ur[j].x = pack_h2(r0.x, r1.x);
            ur[j].y = pack_h2(r0.y, r1.y);
        } else {
            const float2 r0 = *(const float2*)(U + (size_t)w * GATES + gcol);
            ur[j].x = __builtin_bit_cast(unsigned int, r0.x);
            ur[j].y = __builtin_bit_cast(unsigned int, r0.y);
        }
    }

    if (tid < KWORDS) hW[tid] = 0u;     // h_0 = 0
    float cst = 0.f;

    const float* xzb = xz + (size_t)b * T_ * GATES + gcol;
    const bool tanh_gate = (group == 2);

    float2 z0 = make_float2(0.f, 0.f);
    if (red_grp) z0 = *(const float2*)xzb;   // step-0 xz
    __syncthreads();   // one-time init barrier (full semantics, off hot path)

#pragma unroll 1
    for (int t = 0; t < T_; ++t) {
        // ---- dot: z[c0,c0+1] over this thread's k-words (U in regs, h from LDS) ----
        float acc0 = 0.f, acc1 = 0.f;
#pragma unroll
        for (int j = 0; j < WPT; j += 4) {
            const int w = wbase + j;
            const uint4 hw4 = *(const uint4*)&hW[w];    // wave-uniform broadcast
            if constexpr (F16) {
                acc0 = fdot2u(ur[j + 0].x, hw4.x, acc0); acc1 = fdot2u(ur[j + 0].y, hw4.x, acc1);
                acc0 = fdot2u(ur[j + 1].x, hw4.y, acc0); acc1 = fdot2u(ur[j + 1].y, hw4.y, acc1);
                acc0 = fdot2u(ur[j + 2].x, hw4.z, acc0); acc1 = fdot2u(ur[j + 2].y, hw4.z, acc1);
                acc0 = fdot2u(ur[j + 3].x, hw4.w, acc0); acc1 = fdot2u(ur[j + 3].y, hw4.w, acc1);
            } else {
                acc0 += ubits(ur[j + 0].x) * ubits(hw4.x); acc1 += ubits(ur[j + 0].y) * ubits(hw4.x);
                acc0 += ubits(ur[j + 1].x) * ubits(hw4.y); acc1 += ubits(ur[j + 1].y) * ubits(hw4.y);
                acc0 += ubits(ur[j + 2].x) * ubits(hw4.z); acc1 += ubits(ur[j + 2].y) * ubits(hw4.z);
                acc0 += ubits(ur[j + 3].x) * ubits(hw4.w); acc1 += ubits(ur[j + 3].y) * ubits(hw4.w);
            }
        }
        if (!red_grp) zpart[kq * CP + cp] = make_float2(acc0, acc1);
        bar_lds();          // bar1 (LDS: zpart)

        // ---- reduce + activations + xz prefetch (last k-group) ----
        if (red_grp) {
            float zx = z0.x + acc0;
            float zy = z0.y + acc1;
#pragma unroll
            for (int r = 0; r < NKG - 1; ++r) {
                const float2 p = zpart[r * CP + cp];
                zx += p.x; zy += p.y;
            }
            if (t + 1 < T_) z0 = *(const float2*)(xzb + (size_t)(t + 1) * GATES);
            float ax, ay;
            if (tanh_gate) { ax = ftanh(zx); ay = ftanh(zy); }
            else           { ax = fsig(zx);  ay = fsig(zy);  }
            *(float2*)&act_sh[c0] = make_float2(ax, ay);
        }
        bar_lds();          // bar2 (LDS: act_sh) -- no vmcnt drain: z0 prefetch stays in flight

        // ---- cell update (wave 0, lanes < HB) ----
        float hnew = 0.f;
        if (tid < HB) {
            const float ig = act_sh[tid];
            const float fg = act_sh[HB + tid];
            const float gg = act_sh[2 * HB + tid];
            const float og = act_sh[3 * HB + tid];
            cst = fg * cst + ig * gg;
            hnew = og * ftanh(cst);
            if (out_last && t == T_ - 1) out_last[(size_t)b * HN + q * HB + tid] = hnew;
        }

        if (t < T_ - 1) {
            const int s = t & 1;
            unsigned int* hslot = hbuf + (size_t)s * B_ * HN + b * HN;
            const unsigned int tag = (unsigned int)(t + 1);

            // publish own h slice as tagged words (fire-and-forget)
            if (tid < HB) {
                const unsigned int word = (tag << 16) | (unsigned int)f2h_bits(hnew);
                __hip_atomic_store(&hslot[q * HB + tid], word,
                                   __ATOMIC_RELAXED, __HIP_MEMORY_SCOPE_AGENT);
            }
            // hout store (off critical path, no longer drained at bar3)
            if (hout && tid < HB)
                hout[((size_t)b * T_ + t) * HN + q * HB + tid] = hnew;

            // pull full h: load + retry until tags fresh (wave 0)
            if (tid < 64) {
                const unsigned long long* hq = (const unsigned long long*)hslot;
                if constexpr (F16) {
                    unsigned long long vA = __hip_atomic_load(&hq[2 * tid],
                        __ATOMIC_RELAXED, __HIP_MEMORY_SCOPE_AGENT);
                    unsigned long long vB = __hip_atomic_load(&hq[2 * tid + 1],
                        __ATOMIC_RELAXED, __HIP_MEMORY_SCOPE_AGENT);
                    while (((vA >> 16) & 0xffffu) != tag || (vA >> 48) != tag)
                        vA = __hip_atomic_load(&hq[2 * tid],
                            __ATOMIC_RELAXED, __HIP_MEMORY_SCOPE_AGENT);
                    while (((vB >> 16) & 0xffffu) != tag || (vB >> 48) != tag)
                        vB = __hip_atomic_load(&hq[2 * tid + 1],
                            __ATOMIC_RELAXED, __HIP_MEMORY_SCOPE_AGENT);
                    hW[2 * tid] = (unsigned int)(vA & 0xffffu) |
                                  ((unsigned int)((vA >> 32) & 0xffffu) << 16);
                    hW[2 * tid + 1] = (unsigned int)(vB & 0xffffu) |
                                      ((unsigned int)((vB >> 32) & 0xffffu) << 16);
                } else {
                    unsigned long long v = __hip_atomic_load(&hq[tid],
                        __ATOMIC_RELAXED, __HIP_MEMORY_SCOPE_AGENT);
                    while (((v >> 16) & 0xffffu) != tag || (v >> 48) != tag)
                        v = __hip_atomic_load(&hq[tid],
                            __ATOMIC_RELAXED, __HIP_MEMORY_SCOPE_AGENT);
                    hW[2 * tid] = __builtin_bit_cast(unsigned int,
                        h2f_bits((unsigned int)v));
                    hW[2 * tid + 1] = __builtin_bit_cast(unsigned int,
                        h2f_bits((unsigned int)(v >> 32)));
                }
            }
            bar_lds();      // bar3 (LDS: hW) -- publish/hout stores stay in flight
        } else if (hout && tid < HB) {
            hout[((size_t)b * T_ + t) * HN + q * HB + tid] = hnew;
        }
    }
}

// ---------------------------------------------------------------------------
// Launch
// ---------------------------------------------------------------------------
extern "C" void kernel_launch(void* const* d_in, const int* in_sizes, int n_in,
                              void* d_out, int out_size, void* d_ws, size_t ws_size,
                              hipStream_t stream)
{
    const float* x  = (const float*)d_in[0];
    const float* W0 = (const float*)d_in[1];
    const float* U0 = (const float*)d_in[2];
    const float* b0 = (const float*)d_in[3];
    const float* W1 = (const float*)d_in[4];
    const float* U1 = (const float*)d_in[5];
    const float* b1 = (const float*)d_in[6];
    const float* W2 = (const float*)d_in[7];
    const float* U2 = (const float*)d_in[8];
    const float* b2 = (const float*)d_in[9];
    const float* m0 = (const float*)d_in[10];
    const float* m1 = (const float*)d_in[11];
    const float* m2 = (const float*)d_in[12];
    float* out = (float*)d_out;

    // workspace layout:
    //   xz    : 134217728 B   (64*512*1024 floats, reused by all 3 layers)
    //   h0    :  33554432 B
    //   h1    :  33554432 B
    //   hbuf  : 3 regions x 131072 B (2 x 64 x 256 tagged words per layer)
    char* ws = (char*)d_ws;
    float* xz = (float*)ws;
    float* h0 = (float*)(ws + 134217728);
    float* h1 = (float*)(ws + 134217728 + 33554432);
    unsigned int* hb0 = (unsigned int*)(ws + 134217728 + 2 * 33554432);
    unsigned int* hb1 = hb0 + 2 * B_ * 256;
    unsigned int* hb2 = hb1 + 2 * B_ * 256;

    const int M = B_ * T_;  // 32768

    // Layer 0
    gemm_mask_f16<<<dim3(1024 / 64, M / 64), 256, 0, stream>>>(x, W0, b0, m0, xz, M, 1024, 128);
    lstm_rec_v12<256, true><<<256, 1024, 0, stream>>>(xz, U0, h0, nullptr, hb0);

    // Layer 1
    gemm_mask_f16<<<dim3(1024 / 64, M / 64), 256, 0, stream>>>(h0, W1, b1, m1, xz, M, 1024, 256);
    lstm_rec_v12<256, true><<<256, 1024, 0, stream>>>(xz, U1, h1, nullptr, hb1);

    // Layer 2 (H=128, fp32 compute, fp16 exchange), emit last h only
    gemm_mask_f16<<<dim3(512 / 64, M / 64), 256, 0, stream>>>(h1, W2, b2, m2, xz, M, 512, 256);
    lstm_rec_v12<128, false><<<256, 1024, 0, stream>>>(xz, U2, nullptr, out, hb2);
}

// Round 4
// 2434.078 us; speedup vs baseline: 1.2753x; 1.0962x over previous
//
#include <hip/hip_runtime.h>
#include <hip/hip_fp16.h>
#include <math.h>

#define B_ 64
#define T_ 512

typedef _Float16 h2_t __attribute__((ext_vector_type(2)));

__device__ __forceinline__ float fdot2u(unsigned int a, unsigned int b, float c) {
#if __has_builtin(__builtin_amdgcn_fdot2)
    return __builtin_amdgcn_fdot2(__builtin_bit_cast(h2_t, a),
                                  __builtin_bit_cast(h2_t, b), c, false);
#else
    const __half2 ah = __builtin_bit_cast(__half2, a);
    const __half2 bh = __builtin_bit_cast(__half2, b);
    const float2 af = __half22float2(ah), bf = __half22float2(bh);
    return c + af.x * bf.x + af.y * bf.y;
#endif
}
__device__ __forceinline__ unsigned int pack_h2(float x, float y) {
    const __half2 h = __float22half2_rn(make_float2(x, y));
    return __builtin_bit_cast(unsigned int, h);
}
__device__ __forceinline__ float ubits(unsigned int a) { return __builtin_bit_cast(float, a); }
__device__ __forceinline__ unsigned short f2h_bits(float x) {
    return __builtin_bit_cast(unsigned short, (_Float16)x);
}
__device__ __forceinline__ float h2f_bits(unsigned int bits) {
    return (float)__builtin_bit_cast(_Float16, (unsigned short)(bits & 0xffffu));
}

__device__ __forceinline__ float fsig(float z) { return 1.f / (1.f + __expf(-z)); }
__device__ __forceinline__ float ftanh(float z) {
    const float e = __expf(2.f * z);
    return 1.f - 2.f / (e + 1.f);
}

// LDS-only barrier (v12): lgkmcnt(0) + s_barrier, no vmcnt drain.
__device__ __forceinline__ void bar_lds() {
    asm volatile("s_waitcnt lgkmcnt(0)" ::: "memory");
    __builtin_amdgcn_s_barrier();
    asm volatile("" ::: "memory");
}

// ---------------------------------------------------------------------------
// GEMM v2: C[M,N] = (A[M,K]*mask)@W[K,N] + bias, packed-fp16 dot2 inner loop.
// 64x64 tile, TK=32 (16 k-pairs), 256 threads, 4x4 microtile. (unchanged)
// ---------------------------------------------------------------------------
__global__ __launch_bounds__(256) void gemm_mask_f16(
    const float* __restrict__ A, const float* __restrict__ W,
    const float* __restrict__ bias, const float* __restrict__ mask,
    float* __restrict__ C, int M, int N, int K)
{
    const int TM = 64, TN = 64, TK = 32, KP = 16;
    __shared__ __align__(16) unsigned int As2[KP][68];
    __shared__ __align__(16) unsigned int Bs2[KP][68];

    const int tid = threadIdx.x;
    const int bn = blockIdx.x;
    const int bm = blockIdx.y;
    const int row0 = bm * TM;
    const int b = row0 / T_;

    const int ty = tid >> 4;
    const int tx = tid & 15;
    const int m0 = ty * 4;
    const int n0 = tx * 4;

    float acc[4][4];
#pragma unroll
    for (int i = 0; i < 4; i++)
#pragma unroll
        for (int j = 0; j < 4; j++) acc[i][j] = 0.f;

    for (int kk = 0; kk < K; kk += TK) {
        {
            const int m = tid >> 2;
            const int kq = (tid & 3) * 8;
            const float4 mv0 = *(const float4*)(mask + (size_t)b * K + kk + kq);
            const float4 mv1 = *(const float4*)(mask + (size_t)b * K + kk + kq + 4);
            const float4 a0 = *(const float4*)(A + (size_t)(row0 + m) * K + kk + kq);
            const float4 a1 = *(const float4*)(A + (size_t)(row0 + m) * K + kk + kq + 4);
            As2[kq / 2 + 0][m] = pack_h2(a0.x * mv0.x, a0.y * mv0.y);
            As2[kq / 2 + 1][m] = pack_h2(a0.z * mv0.z, a0.w * mv0.w);
            As2[kq / 2 + 2][m] = pack_h2(a1.x * mv1.x, a1.y * mv1.y);
            As2[kq / 2 + 3][m] = pack_h2(a1.z * mv1.z, a1.w * mv1.w);
        }
        {
            const int kp = tid >> 4;
            const int nq = (tid & 15) * 4;
            const float4 w0 = *(const float4*)(W + (size_t)(kk + 2 * kp) * N + bn * TN + nq);
            const float4 w1 = *(const float4*)(W + (size_t)(kk + 2 * kp + 1) * N + bn * TN + nq);
            uint4 pv;
            pv.x = pack_h2(w0.x, w1.x);
            pv.y = pack_h2(w0.y, w1.y);
            pv.z = pack_h2(w0.z, w1.z);
            pv.w = pack_h2(w0.w, w1.w);
            *(uint4*)&Bs2[kp][nq] = pv;
        }
        __syncthreads();

#pragma unroll
        for (int kp = 0; kp < KP; kp++) {
            const uint4 a4 = *(const uint4*)&As2[kp][m0];
            const uint4 b4 = *(const uint4*)&Bs2[kp][n0];
            acc[0][0] = fdot2u(a4.x, b4.x, acc[0][0]); acc[0][1] = fdot2u(a4.x, b4.y, acc[0][1]);
            acc[0][2] = fdot2u(a4.x, b4.z, acc[0][2]); acc[0][3] = fdot2u(a4.x, b4.w, acc[0][3]);
            acc[1][0] = fdot2u(a4.y, b4.x, acc[1][0]); acc[1][1] = fdot2u(a4.y, b4.y, acc[1][1]);
            acc[1][2] = fdot2u(a4.y, b4.z, acc[1][2]); acc[1][3] = fdot2u(a4.y, b4.w, acc[1][3]);
            acc[2][0] = fdot2u(a4.z, b4.x, acc[2][0]); acc[2][1] = fdot2u(a4.z, b4.y, acc[2][1]);
            acc[2][2] = fdot2u(a4.z, b4.z, acc[2][2]); acc[2][3] = fdot2u(a4.z, b4.w, acc[2][3]);
            acc[3][0] = fdot2u(a4.w, b4.x, acc[3][0]); acc[3][1] = fdot2u(a4.w, b4.y, acc[3][1]);
            acc[3][2] = fdot2u(a4.w, b4.z, acc[3][2]); acc[3][3] = fdot2u(a4.w, b4.w, acc[3][3]);
        }
        __syncthreads();
    }

    const float4 bv = *(const float4*)(bias + bn * TN + n0);
#pragma unroll
    for (int i = 0; i < 4; i++) {
        float4 v;
        v.x = acc[i][0] + bv.x;
        v.y = acc[i][1] + bv.y;
        v.z = acc[i][2] + bv.z;
        v.w = acc[i][3] + bv.w;
        *(float4*)&C[(size_t)(row0 + m0 + i) * N + bn * TN + n0] = v;
    }
}

// ---------------------------------------------------------------------------
// LSTM recurrence v13: 2-phase step with overlapped exchange.
// Evidence (r3): all three layers run at the SAME 807us despite 2x different
// dot/exchange/LDS sizes -> the step is a fixed serial-latency floor:
// dot -> bar1 -> reduce (LDS RT) -> bar2 -> cell (LDS RT) -> publish -> naked
// L2 round-trip poll -> bar3. v13 restructures:
//  * cell thread u owns ALL 4 gates of unit u: reduces 4 columns directly
//    from scalar zpartS (padded stride, conflict-free), act+cell+publish in
//    one phase -> bar2 and act_sh eliminated (one LDS RT + one barrier saved).
//  * own-quarter h goes straight to LDS (no L2 round trip for local data).
//  * pull of the 3 REMOTE quarters runs in waves 1-2 CONCURRENTLY with the
//    cell wave's reduce+act+cell -> the publish->L2->poll latency hides under
//    ~500cy of local work instead of being appended after it.
// Tag/parity protocol unchanged (skew bound is data-dependency based: my pull
// lanes complete before bar2, which precedes my t+2 publish, which gates any
// sibling's t+3 overwrite of the slot I read -- same induction as v10).
// Every thread passes exactly 2 barriers/step -> no deadlock.
// ---------------------------------------------------------------------------
template <int HN, bool F16>
__global__ __launch_bounds__(1024) void lstm_rec_v13(
    const float* __restrict__ xz,       // [B, T, 4*HN]
    const float* __restrict__ U,        // [HN, 4*HN]
    float* __restrict__ hout,           // [B, T, HN] or nullptr
    float* __restrict__ out_last,       // [B, HN] or nullptr
    unsigned int* __restrict__ hbuf)    // [2][B_*HN] tagged words
{
    constexpr int GATES = 4 * HN;
    constexpr int COLS = HN;            // block's column space (4 gates x HB units)
    constexpr int CP = COLS / 2;        // col-pairs per k-group
    constexpr int NKG = 1024 / CP;      // k-groups (8 for HN=256, 16 for HN=128)
    constexpr int KH = HN / NKG;        // k-values per group
    constexpr int HB = HN / 4;          // units owned by this block
    constexpr int KWORDS = F16 ? HN / 2 : HN;   // hW words
    constexpr int WPT = F16 ? KH / 2 : KH;      // ur words per thread
    constexpr int NKGP = NKG + 1;       // padded stride (floats) in zpartS
    constexpr int NR = 3 * HB / 2;      // remote qwords to pull (96 / 48)

    __shared__ __align__(16) unsigned int hW[KWORDS];
    __shared__ __align__(16) float zpartS[COLS * NKGP];

    const int tid = threadIdx.x;
    const int q = blockIdx.x >> 6;      // quarter 0..3
    const int b = blockIdx.x & 63;      // batch element (siblings 64 apart -> same XCD)

    const int cp = tid % CP;
    const int kq = tid / CP;            // wave-uniform (CP % 64 == 0)
    const int c0 = 2 * cp;
    const int group = c0 / HB;
    const int gcol = group * HN + q * HB + (c0 % HB);
    const int wbase = kq * WPT;

    // ---- one-time: load this thread's U slice into REGISTERS ----
    uint2 ur[WPT];
#pragma unroll
    for (int j = 0; j < WPT; ++j) {
        const int w = wbase + j;
        if constexpr (F16) {
            const float2 r0 = *(const float2*)(U + (size_t)(2 * w) * GATES + gcol);
            const float2 r1 = *(const float2*)(U + (size_t)(2 * w + 1) * GATES + gcol);
            ur[j].x = pack_h2(r0.x, r1.x);
            ur[j].y = pack_h2(r0.y, r1.y);
        } else {
            const float2 r0 = *(const float2*)(U + (size_t)w * GATES + gcol);
            ur[j].x = __builtin_bit_cast(unsigned int, r0.x);
            ur[j].y = __builtin_bit_cast(unsigned int, r0.y);
        }
    }

    if (tid < KWORDS) hW[tid] = 0u;     // h_0 = 0
    float cst = 0.f;

    // cell-lane setup: thread u (< HB) owns unit u; xz cols g*HN + q*HB + u
    const float* xzcell = xz + (size_t)b * T_ * GATES + q * HB + tid;
    float z4[4] = {0.f, 0.f, 0.f, 0.f};
    if (tid < HB) {
#pragma unroll
        for (int g = 0; g < 4; ++g) z4[g] = xzcell[(size_t)g * HN];   // t=0
    }
    __syncthreads();   // one-time init barrier

#pragma unroll 1
    for (int t = 0; t < T_; ++t) {
        // ---- phase A: dot over this thread's k-words; write scalar partials ----
        float acc0 = 0.f, acc1 = 0.f;
#pragma unroll
        for (int j = 0; j < WPT; j += 4) {
            const int w = wbase + j;
            const uint4 hw4 = *(const uint4*)&hW[w];    // wave-uniform broadcast
            if constexpr (F16) {
                acc0 = fdot2u(ur[j + 0].x, hw4.x, acc0); acc1 = fdot2u(ur[j + 0].y, hw4.x, acc1);
                acc0 = fdot2u(ur[j + 1].x, hw4.y, acc0); acc1 = fdot2u(ur[j + 1].y, hw4.y, acc1);
                acc0 = fdot2u(ur[j + 2].x, hw4.z, acc0); acc1 = fdot2u(ur[j + 2].y, hw4.z, acc1);
                acc0 = fdot2u(ur[j + 3].x, hw4.w, acc0); acc1 = fdot2u(ur[j + 3].y, hw4.w, acc1);
            } else {
                acc0 += ubits(ur[j + 0].x) * ubits(hw4.x); acc1 += ubits(ur[j + 0].y) * ubits(hw4.x);
                acc0 += ubits(ur[j + 1].x) * ubits(hw4.y); acc1 += ubits(ur[j + 1].y) * ubits(hw4.y);
                acc0 += ubits(ur[j + 2].x) * ubits(hw4.z); acc1 += ubits(ur[j + 2].y) * ubits(hw4.z);
                acc0 += ubits(ur[j + 3].x) * ubits(hw4.w); acc1 += ubits(ur[j + 3].y) * ubits(hw4.w);
            }
        }
        zpartS[(c0 + 0) * NKGP + kq] = acc0;
        zpartS[(c0 + 1) * NKGP + kq] = acc1;
        bar_lds();          // bar1

        const unsigned int tag = (unsigned int)(t + 1);
        unsigned int* hslot = hbuf + (size_t)(t & 1) * B_ * HN + b * HN;

        if (tid < HB) {
            // ---- cell wave: direct reduce of 4 gate-columns + act + cell ----
            float zg[4];
#pragma unroll
            for (int g = 0; g < 4; ++g) {
                const float* zp = &zpartS[(g * HB + tid) * NKGP];
                float zs = z4[g];
#pragma unroll
                for (int r = 0; r < NKG; ++r) zs += zp[r];
                zg[g] = zs;
            }
            // prefetch next step's xz (consumed next iteration)
            if (t + 1 < T_) {
#pragma unroll
                for (int g = 0; g < 4; ++g)
                    z4[g] = xzcell[(size_t)(t + 1) * GATES + (size_t)g * HN];
            }
            const float ig = fsig(zg[0]);
            const float fg = fsig(zg[1]);
            const float gg = ftanh(zg[2]);
            const float og = fsig(zg[3]);
            cst = fg * cst + ig * gg;
            const float hnew = og * ftanh(cst);

            if (hout) hout[((size_t)b * T_ + t) * HN + q * HB + tid] = hnew;
            if (t == T_ - 1) {
                if (out_last) out_last[(size_t)b * HN + q * HB + tid] = hnew;
            } else {
                const unsigned short h16 = f2h_bits(hnew);
                // publish for siblings (fire-and-forget, tagged)
                __hip_atomic_store(&hslot[q * HB + tid],
                                   ((unsigned int)tag << 16) | (unsigned int)h16,
                                   __ATOMIC_RELAXED, __HIP_MEMORY_SCOPE_AGENT);
                // own quarter goes straight to LDS (no L2 round trip)
                if constexpr (F16) {
                    reinterpret_cast<unsigned short*>(hW)[q * HB + tid] = h16;
                } else {
                    hW[q * HB + tid] = __builtin_bit_cast(unsigned int, hnew);
                }
            }
        } else if (tid >= 64 && tid < 64 + NR && t < T_ - 1) {
            // ---- pull waves (1-2): poll the 3 remote quarters concurrently ----
            const int idx = tid - 64;
            const int qp0 = q * (HB / 2);
            const int p = idx + (idx >= qp0 ? (HB / 2) : 0);   // remote pair index
            const unsigned long long* hq = (const unsigned long long*)hslot;
            unsigned long long v = __hip_atomic_load(&hq[p],
                __ATOMIC_RELAXED, __HIP_MEMORY_SCOPE_AGENT);
            while (((v >> 16) & 0xffffu) != tag || (v >> 48) != tag)
                v = __hip_atomic_load(&hq[p],
                    __ATOMIC_RELAXED, __HIP_MEMORY_SCOPE_AGENT);
            if constexpr (F16) {
                hW[p] = (unsigned int)(v & 0xffffu) |
                        ((unsigned int)((v >> 32) & 0xffffu) << 16);
            } else {
                hW[2 * p + 0] = __builtin_bit_cast(unsigned int, h2f_bits((unsigned int)v));
                hW[2 * p + 1] = __builtin_bit_cast(unsigned int, h2f_bits((unsigned int)(v >> 32)));
            }
        }
        bar_lds();          // bar2 -> next dot sees full h(t+1)
    }
}

// ---------------------------------------------------------------------------
// Launch
// ---------------------------------------------------------------------------
extern "C" void kernel_launch(void* const* d_in, const int* in_sizes, int n_in,
                              void* d_out, int out_size, void* d_ws, size_t ws_size,
                              hipStream_t stream)
{
    const float* x  = (const float*)d_in[0];
    const float* W0 = (const float*)d_in[1];
    const float* U0 = (const float*)d_in[2];
    const float* b0 = (const float*)d_in[3];
    const float* W1 = (const float*)d_in[4];
    const float* U1 = (const float*)d_in[5];
    const float* b1 = (const float*)d_in[6];
    const float* W2 = (const float*)d_in[7];
    const float* U2 = (const float*)d_in[8];
    const float* b2 = (const float*)d_in[9];
    const float* m0 = (const float*)d_in[10];
    const float* m1 = (const float*)d_in[11];
    const float* m2 = (const float*)d_in[12];
    float* out = (float*)d_out;

    // workspace layout:
    //   xz    : 134217728 B   (64*512*1024 floats, reused by all 3 layers)
    //   h0    :  33554432 B
    //   h1    :  33554432 B
    //   hbuf  : 3 regions x 131072 B (2 x 64 x 256 tagged words per layer)
    char* ws = (char*)d_ws;
    float* xz = (float*)ws;
    float* h0 = (float*)(ws + 134217728);
    float* h1 = (float*)(ws + 134217728 + 33554432);
    unsigned int* hb0 = (unsigned int*)(ws + 134217728 + 2 * 33554432);
    unsigned int* hb1 = hb0 + 2 * B_ * 256;
    unsigned int* hb2 = hb1 + 2 * B_ * 256;

    const int M = B_ * T_;  // 32768

    // Layer 0
    gemm_mask_f16<<<dim3(1024 / 64, M / 64), 256, 0, stream>>>(x, W0, b0, m0, xz, M, 1024, 128);
    lstm_rec_v13<256, true><<<256, 1024, 0, stream>>>(xz, U0, h0, nullptr, hb0);

    // Layer 1
    gemm_mask_f16<<<dim3(1024 / 64, M / 64), 256, 0, stream>>>(h0, W1, b1, m1, xz, M, 1024, 256);
    lstm_rec_v13<256, true><<<256, 1024, 0, stream>>>(xz, U1, h1, nullptr, hb1);

    // Layer 2 (H=128, f32 dot, fp16 exchange), emit last h only
    gemm_mask_f16<<<dim3(512 / 64, M / 64), 256, 0, stream>>>(h1, W2, b2, m2, xz, M, 512, 256);
    lstm_rec_v13<128, false><<<256, 1024, 0, stream>>>(xz, U2, nullptr, out, hb2);
}